// Round 18
// baseline (80.778 us; speedup 1.0000x reference)
//
#include <hip/hip_runtime.h>
#include <hip/hip_bf16.h>

// MultiHeadAttention fused forward, MI355X/gfx950.
// B=2, S=2048, D_IN=768, H=12, D=64.  out[b,s,h*64+e] fp32.
//
// Pipeline:
//   1. prep    : x -> bf16 pre-swizzled A-images; W -> pre-swizzled B-images
//                (r16 layouts; r17 frag-major reg-GEMM regressed, reverted).
//   2. proj_qkv: DMA-staged dbuf MFMA GEMM (r6-proven sync).  Q prescaled,
//                K/Vt pre-swizzled images.
//   3. attn    : r18 = r12 mechanism x r14 geometry: 128-row q-tiles (4 waves
//                x 32 rows, 2 groups/wave -> K/V LDS bytes per q-row HALVED),
//                split-K pieces of <=8 iters -> 960 blocks, sizes descending.
//                r16-proven counted-vmcnt + memory-clobber barriers.
//   4. combine : merge 2-4 split partials per (bh, pt>=4) -> out.
//
// Workspace: wtb [0,3538944) | Q [3538944,9830400) | Ksw [9830400,16121856)
//            Vtsw [16121856,22413312) | xb [22413312,28704768)
//            Obuf [28704768,57016320) | mlbuf [57016320,57901056)

typedef short bf16x8 __attribute__((ext_vector_type(8)));
typedef short bf16x4 __attribute__((ext_vector_type(4)));
typedef float f32x4  __attribute__((ext_vector_type(4)));

#define MFMA16(a, b, c)  __builtin_amdgcn_mfma_f32_16x16x32_bf16((a), (b), (c), 0, 0, 0)
#define MFMAK16(a, b, c) __builtin_amdgcn_mfma_f32_16x16x16bf16_1k((a), (b), (c), 0, 0, 0)
#define SCHED_FENCE() __builtin_amdgcn_sched_barrier(0)
#define MEMBAR() asm volatile("s_barrier" ::: "memory")

static __device__ __forceinline__ unsigned short f2bf(float f) {
    unsigned int u = __builtin_bit_cast(unsigned int, f);
    u += 0x7fffu + ((u >> 16) & 1u);
    return (unsigned short)(u >> 16);
}

// XOR swizzle for [row][128B] tiles (conflict-free b128 column slices).
static __device__ __forceinline__ int sw(int row, int cb) {
    return (row << 7) + (cb ^ ((row & 7) << 4));
}

// async 16B global->LDS DMA (HW: wave-uniform LDS base + lane*16)
static __device__ __forceinline__ void gld16(const void* g, void* l) {
    __builtin_amdgcn_global_load_lds(
        (__attribute__((address_space(1))) void*)g,
        (__attribute__((address_space(3))) void*)l, 16, 0, 0);
}

// ---------------------------------------------------------------------------
// Kernel 1 (merged preps).  grid 1200.  (r16 layouts)
// ---------------------------------------------------------------------------
__global__ __launch_bounds__(256) void prep(const float* __restrict__ x,
                                            const float* __restrict__ Wq,
                                            const float* __restrict__ Wk,
                                            const float* __restrict__ Wv,
                                            char* __restrict__ xb,
                                            char* __restrict__ wtb) {
    __shared__ float tile[64][65];
    const int bid = blockIdx.x;
    const int t = threadIdx.x;
    if (bid < 768) {
        const int stile = bid & 63, ks = bid >> 6;
        const int row = t >> 2, k16 = (t & 3) * 16;
        const float* src = x + (size_t)(stile * 64 + row) * 768 + ks * 64 + k16;
        char* img = xb + ((size_t)stile * 12 + ks) * 8192;
        const float4 v0 = *(const float4*)(src);
        const float4 v1 = *(const float4*)(src + 4);
        const float4 v2 = *(const float4*)(src + 8);
        const float4 v3 = *(const float4*)(src + 12);
        bf16x8 o0, o1;
        o0[0] = (short)f2bf(v0.x); o0[1] = (short)f2bf(v0.y);
        o0[2] = (short)f2bf(v0.z); o0[3] = (short)f2bf(v0.w);
        o0[4] = (short)f2bf(v1.x); o0[5] = (short)f2bf(v1.y);
        o0[6] = (short)f2bf(v1.z); o0[7] = (short)f2bf(v1.w);
        o1[0] = (short)f2bf(v2.x); o1[1] = (short)f2bf(v2.y);
        o1[2] = (short)f2bf(v2.z); o1[3] = (short)f2bf(v2.w);
        o1[4] = (short)f2bf(v3.x); o1[5] = (short)f2bf(v3.y);
        o1[6] = (short)f2bf(v3.z); o1[7] = (short)f2bf(v3.w);
        *(bf16x8*)(img + sw(row, k16 * 2)) = o0;
        *(bf16x8*)(img + sw(row, k16 * 2 + 16)) = o1;
    } else {
        const int idx = bid - 768;
        const int wh = idx % 36, dt = idx / 36;
        const int w = wh / 12, h = wh % 12;
        const float* W = (w == 0) ? Wq : (w == 1) ? Wk : Wv;
        for (int i = 0; i < 4; ++i) {
            int c = t + i * 256;
            int d = c >> 4, e4 = (c & 15) * 4;
            const float4 v = *(const float4*)(W + (size_t)(h * 768 + dt * 64 + d) * 64 + e4);
            tile[d][e4 + 0] = v.x; tile[d][e4 + 1] = v.y;
            tile[d][e4 + 2] = v.z; tile[d][e4 + 3] = v.w;
        }
        __syncthreads();
        char* img = wtb + ((size_t)(wh * 12) + dt) * 8192;
        for (int i = 0; i < 4; ++i) {
            int c = t + i * 256;
            int e = c >> 4, d4 = (c & 15) * 4;
            ushort4 o;
            o.x = f2bf(tile[d4 + 0][e]); o.y = f2bf(tile[d4 + 1][e]);
            o.z = f2bf(tile[d4 + 2][e]); o.w = f2bf(tile[d4 + 3][e]);
            *(ushort4*)(img + e * 128 + ((d4 * 2) ^ ((e & 7) << 4))) = o;
        }
    }
}

// ---------------------------------------------------------------------------
// Kernel 2: QKV projection.  grid (64 stile, 12 h), 4 waves, DMA dbuf (r16).
// ---------------------------------------------------------------------------
__global__ __launch_bounds__(256) void proj_qkv(const char* __restrict__ xb,
                                                const char* __restrict__ wtb,
                                                unsigned short* __restrict__ q,
                                                unsigned short* __restrict__ ksw,
                                                char* __restrict__ vsw) {
    __shared__ __align__(16) char smem[65536];   // [2 buf][4 img][8192]
    const int stile = blockIdx.x;
    const int h = blockIdx.y;
    const int t = threadIdx.x;
    const int wave = t >> 6, lane = t & 63;
    const int lhi = lane >> 4, llo = lane & 15;
    const int wr = wave >> 1, wc = wave & 1;

    const char* asrc = xb + (size_t)stile * 12 * 8192;

    f32x4 acc[3][2][2] = {};

    #define STAGE(KS, BUF)                                                       \
        do {                                                                     \
            const char* s0 = asrc + (KS) * 8192;                                 \
            char* d0 = smem + (BUF) * 32768;                                     \
            gld16(s0 + t * 16, d0 + t * 16);                                     \
            gld16(s0 + t * 16 + 4096, d0 + t * 16 + 4096);                       \
            for (int w3 = 0; w3 < 3; ++w3) {                                     \
                const char* s1 = wtb + ((size_t)((w3 * 12 + h) * 12) + (KS)) * 8192; \
                char* d1 = smem + (BUF) * 32768 + (1 + w3) * 8192;               \
                gld16(s1 + t * 16, d1 + t * 16);                                 \
                gld16(s1 + t * 16 + 4096, d1 + t * 16 + 4096);                   \
            }                                                                    \
        } while (0)

    STAGE(0, 0);
    __syncthreads();
    int cur = 0;
    for (int ks = 0; ks < 12; ++ks) {
        if (ks < 11) STAGE(ks + 1, cur ^ 1);   // prefetch overlaps compute below
        char* Alds = smem + cur * 32768;
        #pragma unroll
        for (int kk = 0; kk < 2; ++kk) {
            bf16x8 a[2];
            #pragma unroll
            for (int m = 0; m < 2; ++m)
                a[m] = *(const bf16x8*)(Alds + sw(wr * 32 + m * 16 + llo, kk * 64 + lhi * 16));
            #pragma unroll
            for (int w3 = 0; w3 < 3; ++w3) {
                char* Blds = Alds + (1 + w3) * 8192;
                #pragma unroll
                for (int n = 0; n < 2; ++n) {
                    bf16x8 b = *(const bf16x8*)(Blds + sw(wc * 32 + n * 16 + llo, kk * 64 + lhi * 16));
                    #pragma unroll
                    for (int m = 0; m < 2; ++m)
                        acc[w3][m][n] = MFMA16(a[m], b, acc[w3][m][n]);
                }
            }
        }
        __syncthreads();   // drains DMA + orders buffer reuse
        cur ^= 1;
    }
    #undef STAGE

    const float SCALE_Q = 0.18033688011112042f;  // 0.125 * log2(e)
    const int bglob = stile >> 5, ktile = stile & 31;
    const int bh = bglob * 12 + h;
    #pragma unroll
    for (int m = 0; m < 2; ++m)
        for (int n = 0; n < 2; ++n)
            for (int r = 0; r < 4; ++r) {
                int s = (stile * 64 + wr * 32 + m * 16 + lhi * 4 + r) & 2047;
                int e = wc * 32 + n * 16 + llo;
                q[(size_t)(bh * 2048 + s) * 64 + e] = f2bf(acc[0][m][n][r] * SCALE_Q);
            }
    unsigned short* kdst = ksw + ((size_t)bh * 32 + ktile) * 4096;
    #pragma unroll
    for (int m = 0; m < 2; ++m)
        for (int n = 0; n < 2; ++n)
            for (int r = 0; r < 4; ++r) {
                int kk = wr * 32 + m * 16 + lhi * 4 + r;
                int e = wc * 32 + n * 16 + llo;
                kdst[kk * 64 + (e ^ ((kk & 7) << 3))] = f2bf(acc[1][m][n][r]);
            }
    char* vtimg = smem;
    __syncthreads();
    #pragma unroll
    for (int m = 0; m < 2; ++m)
        for (int n = 0; n < 2; ++n)
            for (int r = 0; r < 4; ++r) {
                int kk = wr * 32 + m * 16 + lhi * 4 + r;
                int e = wc * 32 + n * 16 + llo;
                int pos = (((kk >> 2) & 3) * 32 + (kk >> 4) * 8 + (kk & 3) * 2) ^ ((e & 7) << 4);
                *(unsigned short*)(vtimg + e * 128 + pos) = f2bf(acc[2][m][n][r]);
            }
    __syncthreads();
    {
        char* dst = vsw + ((size_t)bh * 32 + ktile) * 8192;
        #pragma unroll
        for (int i = 0; i < 2; ++i)
            *(float4*)(dst + t * 16 + i * 4096) =
                *(const float4*)(vtimg + t * 16 + i * 4096);
    }
}

// ---------------------------------------------------------------------------
// Kernel 3: flash attention, 128-row q-tiles + split-K pieces (r18).
// grid 960 x 256 thr.  bid -> j = bid/24 (piece rank, sizes descending),
// bh = bid%24.  j -> (pt, p): pt = q-tile 0..15 (rows pt*128..+127),
// p = k-piece (kt in [8p, min(8p+7, 2pt+1)]).  np(pt) = 1,2,3,4 pieces.
// Wave w: 32 rows (2 groups g of 16); diag k-tile = 2pt + (w>>1); waves 0/1
// skip the block's final k-iter (wave-uniform branch).  K/V fragments read
// once per wave, feed both groups.  Counted-vmcnt + MEMBAR (r16-proven).
// Split pieces write unnormalized (O,m,l); pt<=3 single pieces write out.
// ---------------------------------------------------------------------------
__global__ __launch_bounds__(256) void attn(const unsigned short* __restrict__ Q,
                                            const char* __restrict__ Ksw,
                                            const char* __restrict__ Vsw,
                                            float* __restrict__ out,
                                            float* __restrict__ Obuf,
                                            float* __restrict__ mlbuf) {
    __shared__ __align__(16) char smem[32768];  // K dbuf [0,16K) | Vt dbuf [16K,32K)
    const int t = threadIdx.x, wave = t >> 6, lane = t & 63;
    const int lhi = lane >> 4, llo = lane & 15;
    const int bid = blockIdx.x;
    const int j = bid / 24, bh = bid % 24;
    // j -> (pt, p), sizes descending (28 size-8, then 4x6, 4x4, 4x2)
    int pt, p;
    if (j < 24) {
        if (j < 4)       { pt = 15; p = j; }
        else if (j < 16) { int i = j - 4;  pt = 14 - i / 3; p = i % 3; }
        else             { int i = j - 16; pt = 10 - i / 2; p = i % 2; }
    } else if (j < 28) { pt = 6 - (j - 24); p = 0; }
    else {
        int grp = (j - 28) >> 2, i = (j - 28) & 3;
        pt = (14 - grp) - 4 * i;
        p = 3 - i;
    }
    const bool split = (pt >= 4);
    const int kts = p * 8;
    const int kteB = min(p * 8 + 7, 2 * pt + 1);   // block staging range
    const int ktmax_w = 2 * pt + (wave >> 1);      // wave's diag k-tile
    const int kteW = min(kteB, ktmax_w);           // wave compute range

    const unsigned short* Qg = Q + (size_t)bh * 2048 * 64;
    const char* Kg = Ksw + (size_t)bh * 32 * 8192;
    const char* Vg = Vsw + (size_t)bh * 32 * 8192;

    const int q0 = pt * 128 + wave * 32;           // wave's 32 rows
    bf16x8 qa[2][2];
    #pragma unroll
    for (int g = 0; g < 2; ++g)
        #pragma unroll
        for (int kk = 0; kk < 2; ++kk)
            qa[g][kk] = *(const bf16x8*)(Qg + (size_t)(q0 + g * 16 + llo) * 64 + kk * 32 + lhi * 8);

    f32x4 acc[2][4] = {};                          // acc[g][n][r]: e=n*16+lhi*4+r, q=llo
    float m_r[2] = {-1e30f, -1e30f}, l_r[2] = {0.f, 0.f};

    #define ASTAGE(KT, BUF)                                              \
        do {                                                             \
            const char* ks_ = Kg + (size_t)(KT) * 8192;                  \
            const char* vs_ = Vg + (size_t)(KT) * 8192;                  \
            char* kd = smem + (BUF) * 8192;                              \
            char* vd = smem + 16384 + (BUF) * 8192;                      \
            gld16(ks_ + t * 16, kd + t * 16);                            \
            gld16(ks_ + t * 16 + 4096, kd + t * 16 + 4096);              \
            gld16(vs_ + t * 16, vd + t * 16);                            \
            gld16(vs_ + t * 16 + 4096, vd + t * 16 + 4096);              \
        } while (0)

    ASTAGE(kts, 0);
    SCHED_FENCE();
    int cur = 0;
    for (int kt = kts; kt <= kteB; ++kt) {
        if (kt < kteB) ASTAGE(kt + 1, cur ^ 1);    // prefetch: stays in flight
        SCHED_FENCE();
        if (kt < kteB) asm volatile("s_waitcnt vmcnt(4)" ::: "memory");
        else           asm volatile("s_waitcnt vmcnt(0)" ::: "memory");
        MEMBAR();                                  // current tile fully staged
        SCHED_FENCE();
        if (kt <= kteW) {                          // waves 0/1 skip final block iter
            char* Kb = smem + cur * 8192;
            char* Vb = smem + 16384 + cur * 8192;

            // S^T = K Q^T for both groups; K fragments read once
            f32x4 sc[2][4] = {};
            __builtin_amdgcn_s_setprio(1);
            #pragma unroll
            for (int n = 0; n < 4; ++n) {
                #pragma unroll
                for (int kk = 0; kk < 2; ++kk) {
                    bf16x8 bk = *(const bf16x8*)(Kb + sw(n * 16 + llo, kk * 64 + lhi * 16));
                    sc[0][n] = MFMA16(bk, qa[0][kk], sc[0][n]);
                    sc[1][n] = MFMA16(bk, qa[1][kk], sc[1][n]);
                }
            }
            __builtin_amdgcn_s_setprio(0);
            if (kt == ktmax_w) {   // diag tile (same for both groups)
                #pragma unroll
                for (int g = 0; g < 2; ++g)
                    #pragma unroll
                    for (int n = 0; n < 4; ++n)
                        #pragma unroll
                        for (int r = 0; r < 4; ++r)
                            if (kt * 64 + n * 16 + lhi * 4 + r > q0 + g * 16 + llo)
                                sc[g][n][r] = -1e30f;
            }
            float pmax[2];
            #pragma unroll
            for (int g = 0; g < 2; ++g)
                pmax[g] = fmaxf(
                    fmaxf(fmaxf(fmaxf(sc[g][0][0], sc[g][0][1]), fmaxf(sc[g][0][2], sc[g][0][3])),
                          fmaxf(fmaxf(sc[g][1][0], sc[g][1][1]), fmaxf(sc[g][1][2], sc[g][1][3]))),
                    fmaxf(fmaxf(fmaxf(sc[g][2][0], sc[g][2][1]), fmaxf(sc[g][2][2], sc[g][2][3])),
                          fmaxf(fmaxf(sc[g][3][0], sc[g][3][1]), fmaxf(sc[g][3][2], sc[g][3][3]))));
            if (__any(pmax[0] > m_r[0] + 8.0f || pmax[1] > m_r[1] + 8.0f)) {
                #pragma unroll
                for (int g = 0; g < 2; ++g) {
                    float tm = fmaxf(pmax[g], __shfl_xor(pmax[g], 16, 64));
                    tm = fmaxf(tm, __shfl_xor(tm, 32, 64));
                    float nm = fmaxf(m_r[g], tm);
                    float corr = exp2f(m_r[g] - nm);
                    m_r[g] = nm;
                    l_r[g] *= corr;
                    #pragma unroll
                    for (int n = 0; n < 4; ++n)
                        #pragma unroll
                        for (int r = 0; r < 4; ++r) acc[g][n][r] *= corr;
                }
            }
            bf16x4 pf[2][4];
            #pragma unroll
            for (int g = 0; g < 2; ++g) {
                float ps = 0.f;
                #pragma unroll
                for (int kb = 0; kb < 4; ++kb) {
                    float p0 = exp2f(sc[g][kb][0] - m_r[g]), p1 = exp2f(sc[g][kb][1] - m_r[g]);
                    float p2 = exp2f(sc[g][kb][2] - m_r[g]), p3 = exp2f(sc[g][kb][3] - m_r[g]);
                    ps += (p0 + p1) + (p2 + p3);
                    unsigned int w0, w1;
                    asm("v_cvt_pk_bf16_f32 %0, %1, %2" : "=v"(w0) : "v"(p0), "v"(p1));
                    asm("v_cvt_pk_bf16_f32 %0, %1, %2" : "=v"(w1) : "v"(p2), "v"(p3));
                    unsigned long long u = ((unsigned long long)w1 << 32) | w0;
                    pf[g][kb] = __builtin_bit_cast(bf16x4, u);
                }
                l_r[g] += ps;
            }
            // O^T += V^T P — V fragments read once, feed both groups
            __builtin_amdgcn_s_setprio(1);
            #pragma unroll
            for (int n = 0; n < 4; ++n) {
                const int row = n * 16 + llo;
                bf16x8 v8a = *(const bf16x8*)(Vb + sw(row, lhi * 32));
                bf16x8 v8b = *(const bf16x8*)(Vb + sw(row, lhi * 32 + 16));
                bf16x4 vf0 = __builtin_shufflevector(v8a, v8a, 0, 1, 2, 3);
                bf16x4 vf1 = __builtin_shufflevector(v8a, v8a, 4, 5, 6, 7);
                bf16x4 vf2 = __builtin_shufflevector(v8b, v8b, 0, 1, 2, 3);
                bf16x4 vf3 = __builtin_shufflevector(v8b, v8b, 4, 5, 6, 7);
                #pragma unroll
                for (int g = 0; g < 2; ++g) {
                    f32x4 a = acc[g][n];
                    a = MFMAK16(vf0, pf[g][0], a);
                    a = MFMAK16(vf1, pf[g][1], a);
                    a = MFMAK16(vf2, pf[g][2], a);
                    a = MFMAK16(vf3, pf[g][3], a);
                    acc[g][n] = a;
                }
            }
            __builtin_amdgcn_s_setprio(0);
        }
        SCHED_FENCE();
        if (kt < kteB) MEMBAR();   // orders next iter's ASTAGE vs this iter's reads
        cur ^= 1;
    }
    #undef ASTAGE
    // epilogue per group
    const int off = (pt < 8) ? (pt - 4) * 2 : (pt < 12) ? 8 + (pt - 8) * 3 : 20 + (pt - 12) * 4;
    const int b = bh / 12, h = bh - b * 12;
    #pragma unroll
    for (int g = 0; g < 2; ++g) {
        float lr = l_r[g];
        lr += __shfl_xor(lr, 16, 64);
        lr += __shfl_xor(lr, 32, 64);
        if (split) {
            const int slot = bh * 36 + off + p;
            float* Ob = Obuf + (size_t)slot * 8192;
            const int qrow = wave * 32 + g * 16 + llo;   // 0..127 within tile
            #pragma unroll
            for (int n = 0; n < 4; ++n) {
                float4 o;
                o.x = acc[g][n][0]; o.y = acc[g][n][1];
                o.z = acc[g][n][2]; o.w = acc[g][n][3];
                *(float4*)(Ob + qrow * 64 + n * 16 + lhi * 4) = o;
            }
            if (lhi == 0) {
                float2 ml; ml.x = m_r[g]; ml.y = lr;
                *(float2*)(mlbuf + (size_t)slot * 256 + qrow * 2) = ml;
            }
        } else {
            const float inv = 1.0f / lr;
            const int qrow = q0 + g * 16 + llo;
            #pragma unroll
            for (int n = 0; n < 4; ++n) {
                float4 o;
                o.x = acc[g][n][0] * inv; o.y = acc[g][n][1] * inv;
                o.z = acc[g][n][2] * inv; o.w = acc[g][n][3] * inv;
                *(float4*)(out + (size_t)(b * 2048 + qrow) * 768 + h * 64 + n * 16 + lhi * 4) = o;
            }
        }
    }
}

// ---------------------------------------------------------------------------
// Kernel 4: combine np (2..4) split partials.  grid 288 (24 bh x 12 pt), 256 thr.
// Thread: row r = t>>1 (0..127), col half = (t&1)*32.
// ---------------------------------------------------------------------------
__global__ __launch_bounds__(256) void combine(const float* __restrict__ Obuf,
                                               const float* __restrict__ mlbuf,
                                               float* __restrict__ out) {
    const int bid = blockIdx.x;
    const int bh = bid % 24, pt = 4 + bid / 24;
    const int np = (pt < 8) ? 2 : (pt < 12) ? 3 : 4;
    const int off = (pt < 8) ? (pt - 4) * 2 : (pt < 12) ? 8 + (pt - 8) * 3 : 20 + (pt - 12) * 4;
    const int base = bh * 36 + off;
    const int b = bh / 12, h = bh - b * 12;
    const int t = threadIdx.x;
    const int r = t >> 1, c0 = (t & 1) * 32;

    float m[4], l[4];
    float mm = -1e30f;
    for (int i = 0; i < np; ++i) {
        float2 ml = *(const float2*)(mlbuf + (size_t)(base + i) * 256 + r * 2);
        m[i] = ml.x; l[i] = ml.y;
        mm = fmaxf(mm, ml.x);
    }
    float L = 0.f, w[4];
    for (int i = 0; i < np; ++i) { w[i] = exp2f(m[i] - mm); L += l[i] * w[i]; }
    const float inv = 1.0f / L;

    float4 o[8];
    {
        const float* s = Obuf + (size_t)base * 8192 + r * 64 + c0;
        const float wi = w[0] * inv;
        #pragma unroll
        for (int k = 0; k < 8; ++k) {
            float4 a = *(const float4*)(s + k * 4);
            o[k].x = a.x * wi; o[k].y = a.y * wi; o[k].z = a.z * wi; o[k].w = a.w * wi;
        }
    }
    for (int i = 1; i < np; ++i) {
        const float* s = Obuf + (size_t)(base + i) * 8192 + r * 64 + c0;
        const float wi = w[i] * inv;
        #pragma unroll
        for (int k = 0; k < 8; ++k) {
            float4 a = *(const float4*)(s + k * 4);
            o[k].x += a.x * wi; o[k].y += a.y * wi; o[k].z += a.z * wi; o[k].w += a.w * wi;
        }
    }
    float* dst = out + (size_t)(b * 2048 + pt * 128 + r) * 768 + h * 64 + c0;
    #pragma unroll
    for (int k = 0; k < 8; ++k) *(float4*)(dst + k * 4) = o[k];
}

// ---------------------------------------------------------------------------
extern "C" void kernel_launch(void* const* d_in, const int* in_sizes, int n_in,
                              void* d_out, int out_size, void* d_ws, size_t ws_size,
                              hipStream_t stream) {
    const float* x  = (const float*)d_in[0];
    const float* Wq = (const float*)d_in[1];
    const float* Wk = (const float*)d_in[2];
    const float* Wv = (const float*)d_in[3];
    float* out = (float*)d_out;

    char* ws = (char*)d_ws;
    char*           wtb   = ws;                                 // 3.54 MB
    unsigned short* q     = (unsigned short*)(ws + 3538944);    // 6.29 MB
    unsigned short* ksw   = (unsigned short*)(ws + 9830400);    // 6.29 MB
    char*           vsw   = (char*)(ws + 16121856);             // 6.29 MB
    char*           xb    = (char*)(ws + 22413312);             // 6.29 MB
    float*          Obuf  = (float*)(ws + 28704768);            // 28.31 MB (864 x 32KB)
    float*          mlbuf = (float*)(ws + 57016320);            // 0.88 MB (864 x 1KB)
    // requires ws_size >= 57901056 bytes

    hipLaunchKernelGGL(prep, dim3(1200), dim3(256), 0, stream, x, Wq, Wk, Wv, xb, wtb);
    hipLaunchKernelGGL(proj_qkv, dim3(64, 12), dim3(256), 0, stream,
                       xb, wtb, q, ksw, vsw);
    hipLaunchKernelGGL(attn, dim3(960), dim3(256), 0, stream,
                       q, (const char*)ksw, vsw, out, Obuf, mlbuf);
    hipLaunchKernelGGL(combine, dim3(288), dim3(256), 0, stream, Obuf, mlbuf, out);
}

// Round 19
// 74.259 us; speedup vs baseline: 1.0878x; 1.0878x over previous
//
#include <hip/hip_runtime.h>
#include <hip/hip_bf16.h>

// MultiHeadAttention fused forward, MI355X/gfx950.
// B=2, S=2048, D_IN=768, H=12, D=64.  out[b,s,h*64+e] fp32.
//
// Pipeline:
//   1. prep    : x -> bf16 pre-swizzled A-images; W -> pre-swizzled B-images.
//   2. proj_qkv: DMA-staged dbuf MFMA GEMM (r6-proven sync).  Q prescaled,
//                K/Vt pre-swizzled images.
//   3. attn    : split-K flash attention (r14 piece table / boustrophedon LPT,
//                68.4us-proven) + r19 2-STAGE SOFTWARE PIPELINE: QK^T of tile
//                t+1 issues BEFORE softmax of tile t, so the MFMA pipe (QK+PV)
//                runs concurrently with the VALU softmax instead of serially.
//                Scores double-buffered in registers; K/V LDS dbuf with
//                stage(t+2) after a write-after-read barrier.
//   4. combine : merge split partials -> out.
//
// Workspace: wtb [0,3538944) | Q [3538944,9830400) | Ksw [9830400,16121856)
//            Vtsw [16121856,22413312) | xb [22413312,28704768)
//            Obuf [28704768,41287680) | mlbuf [41287680,41680896)

typedef short bf16x8 __attribute__((ext_vector_type(8)));
typedef short bf16x4 __attribute__((ext_vector_type(4)));
typedef float f32x4  __attribute__((ext_vector_type(4)));

#define MFMA16(a, b, c)  __builtin_amdgcn_mfma_f32_16x16x32_bf16((a), (b), (c), 0, 0, 0)
#define MFMAK16(a, b, c) __builtin_amdgcn_mfma_f32_16x16x16bf16_1k((a), (b), (c), 0, 0, 0)

static __device__ __forceinline__ unsigned short f2bf(float f) {
    unsigned int u = __builtin_bit_cast(unsigned int, f);
    u += 0x7fffu + ((u >> 16) & 1u);
    return (unsigned short)(u >> 16);
}

// XOR swizzle for [row][128B] tiles (conflict-free b128 column slices).
static __device__ __forceinline__ int sw(int row, int cb) {
    return (row << 7) + (cb ^ ((row & 7) << 4));
}

// async 16B global->LDS DMA (HW: wave-uniform LDS base + lane*16)
static __device__ __forceinline__ void gld16(const void* g, void* l) {
    __builtin_amdgcn_global_load_lds(
        (__attribute__((address_space(1))) void*)g,
        (__attribute__((address_space(3))) void*)l, 16, 0, 0);
}

// ---------------------------------------------------------------------------
// Kernel 1 (merged preps).  grid 1200.
// ---------------------------------------------------------------------------
__global__ __launch_bounds__(256) void prep(const float* __restrict__ x,
                                            const float* __restrict__ Wq,
                                            const float* __restrict__ Wk,
                                            const float* __restrict__ Wv,
                                            char* __restrict__ xb,
                                            char* __restrict__ wtb) {
    __shared__ float tile[64][65];
    const int bid = blockIdx.x;
    const int t = threadIdx.x;
    if (bid < 768) {
        const int stile = bid & 63, ks = bid >> 6;
        const int row = t >> 2, k16 = (t & 3) * 16;
        const float* src = x + (size_t)(stile * 64 + row) * 768 + ks * 64 + k16;
        char* img = xb + ((size_t)stile * 12 + ks) * 8192;
        const float4 v0 = *(const float4*)(src);
        const float4 v1 = *(const float4*)(src + 4);
        const float4 v2 = *(const float4*)(src + 8);
        const float4 v3 = *(const float4*)(src + 12);
        bf16x8 o0, o1;
        o0[0] = (short)f2bf(v0.x); o0[1] = (short)f2bf(v0.y);
        o0[2] = (short)f2bf(v0.z); o0[3] = (short)f2bf(v0.w);
        o0[4] = (short)f2bf(v1.x); o0[5] = (short)f2bf(v1.y);
        o0[6] = (short)f2bf(v1.z); o0[7] = (short)f2bf(v1.w);
        o1[0] = (short)f2bf(v2.x); o1[1] = (short)f2bf(v2.y);
        o1[2] = (short)f2bf(v2.z); o1[3] = (short)f2bf(v2.w);
        o1[4] = (short)f2bf(v3.x); o1[5] = (short)f2bf(v3.y);
        o1[6] = (short)f2bf(v3.z); o1[7] = (short)f2bf(v3.w);
        *(bf16x8*)(img + sw(row, k16 * 2)) = o0;
        *(bf16x8*)(img + sw(row, k16 * 2 + 16)) = o1;
    } else {
        const int idx = bid - 768;
        const int wh = idx % 36, dt = idx / 36;
        const int w = wh / 12, h = wh % 12;
        const float* W = (w == 0) ? Wq : (w == 1) ? Wk : Wv;
        for (int i = 0; i < 4; ++i) {
            int c = t + i * 256;
            int d = c >> 4, e4 = (c & 15) * 4;
            const float4 v = *(const float4*)(W + (size_t)(h * 768 + dt * 64 + d) * 64 + e4);
            tile[d][e4 + 0] = v.x; tile[d][e4 + 1] = v.y;
            tile[d][e4 + 2] = v.z; tile[d][e4 + 3] = v.w;
        }
        __syncthreads();
        char* img = wtb + ((size_t)(wh * 12) + dt) * 8192;
        for (int i = 0; i < 4; ++i) {
            int c = t + i * 256;
            int e = c >> 4, d4 = (c & 15) * 4;
            ushort4 o;
            o.x = f2bf(tile[d4 + 0][e]); o.y = f2bf(tile[d4 + 1][e]);
            o.z = f2bf(tile[d4 + 2][e]); o.w = f2bf(tile[d4 + 3][e]);
            *(ushort4*)(img + e * 128 + ((d4 * 2) ^ ((e & 7) << 4))) = o;
        }
    }
}

// ---------------------------------------------------------------------------
// Kernel 2: QKV projection.  grid (64 stile, 12 h), 4 waves, DMA dbuf.
// ---------------------------------------------------------------------------
__global__ __launch_bounds__(256) void proj_qkv(const char* __restrict__ xb,
                                                const char* __restrict__ wtb,
                                                unsigned short* __restrict__ q,
                                                unsigned short* __restrict__ ksw,
                                                char* __restrict__ vsw) {
    __shared__ __align__(16) char smem[65536];   // [2 buf][4 img][8192]
    const int stile = blockIdx.x;
    const int h = blockIdx.y;
    const int t = threadIdx.x;
    const int wave = t >> 6, lane = t & 63;
    const int lhi = lane >> 4, llo = lane & 15;
    const int wr = wave >> 1, wc = wave & 1;

    const char* asrc = xb + (size_t)stile * 12 * 8192;

    f32x4 acc[3][2][2] = {};

    #define STAGE(KS, BUF)                                                       \
        do {                                                                     \
            const char* s0 = asrc + (KS) * 8192;                                 \
            char* d0 = smem + (BUF) * 32768;                                     \
            gld16(s0 + t * 16, d0 + t * 16);                                     \
            gld16(s0 + t * 16 + 4096, d0 + t * 16 + 4096);                       \
            for (int w3 = 0; w3 < 3; ++w3) {                                     \
                const char* s1 = wtb + ((size_t)((w3 * 12 + h) * 12) + (KS)) * 8192; \
                char* d1 = smem + (BUF) * 32768 + (1 + w3) * 8192;               \
                gld16(s1 + t * 16, d1 + t * 16);                                 \
                gld16(s1 + t * 16 + 4096, d1 + t * 16 + 4096);                   \
            }                                                                    \
        } while (0)

    STAGE(0, 0);
    __syncthreads();
    int cur = 0;
    for (int ks = 0; ks < 12; ++ks) {
        if (ks < 11) STAGE(ks + 1, cur ^ 1);   // prefetch overlaps compute below
        char* Alds = smem + cur * 32768;
        #pragma unroll
        for (int kk = 0; kk < 2; ++kk) {
            bf16x8 a[2];
            #pragma unroll
            for (int m = 0; m < 2; ++m)
                a[m] = *(const bf16x8*)(Alds + sw(wr * 32 + m * 16 + llo, kk * 64 + lhi * 16));
            #pragma unroll
            for (int w3 = 0; w3 < 3; ++w3) {
                char* Blds = Alds + (1 + w3) * 8192;
                #pragma unroll
                for (int n = 0; n < 2; ++n) {
                    bf16x8 b = *(const bf16x8*)(Blds + sw(wc * 32 + n * 16 + llo, kk * 64 + lhi * 16));
                    #pragma unroll
                    for (int m = 0; m < 2; ++m)
                        acc[w3][m][n] = MFMA16(a[m], b, acc[w3][m][n]);
                }
            }
        }
        __syncthreads();   // drains DMA + orders buffer reuse
        cur ^= 1;
    }
    #undef STAGE

    const float SCALE_Q = 0.18033688011112042f;  // 0.125 * log2(e)
    const int bglob = stile >> 5, ktile = stile & 31;
    const int bh = bglob * 12 + h;
    #pragma unroll
    for (int m = 0; m < 2; ++m)
        for (int n = 0; n < 2; ++n)
            for (int r = 0; r < 4; ++r) {
                int s = (stile * 64 + wr * 32 + m * 16 + lhi * 4 + r) & 2047;
                int e = wc * 32 + n * 16 + llo;
                q[(size_t)(bh * 2048 + s) * 64 + e] = f2bf(acc[0][m][n][r] * SCALE_Q);
            }
    unsigned short* kdst = ksw + ((size_t)bh * 32 + ktile) * 4096;
    #pragma unroll
    for (int m = 0; m < 2; ++m)
        for (int n = 0; n < 2; ++n)
            for (int r = 0; r < 4; ++r) {
                int kk = wr * 32 + m * 16 + lhi * 4 + r;
                int e = wc * 32 + n * 16 + llo;
                kdst[kk * 64 + (e ^ ((kk & 7) << 3))] = f2bf(acc[1][m][n][r]);
            }
    char* vtimg = smem;
    __syncthreads();
    #pragma unroll
    for (int m = 0; m < 2; ++m)
        for (int n = 0; n < 2; ++n)
            for (int r = 0; r < 4; ++r) {
                int kk = wr * 32 + m * 16 + lhi * 4 + r;
                int e = wc * 32 + n * 16 + llo;
                int pos = (((kk >> 2) & 3) * 32 + (kk >> 4) * 8 + (kk & 3) * 2) ^ ((e & 7) << 4);
                *(unsigned short*)(vtimg + e * 128 + pos) = f2bf(acc[2][m][n][r]);
            }
    __syncthreads();
    {
        char* dst = vsw + ((size_t)bh * 32 + ktile) * 8192;
        #pragma unroll
        for (int i = 0; i < 2; ++i)
            *(float4*)(dst + t * 16 + i * 4096) =
                *(const float4*)(vtimg + t * 16 + i * 4096);
    }
}

// ---------------------------------------------------------------------------
// Kernel 3: split-K flash attention with 2-stage register pipeline (r19).
// grid 1152 x 256 thr, r14 boustrophedon LPT piece table.
// Loop invariant entering iter kt: scA = S(kt); V(kt) in buf[curV];
// tile kt+1 DMA in flight to buf[curV^1].
// Iter: sync; QK(kt+1)->scB (MFMA, issues first); mask+softmax(scA) (VALU,
// overlaps); PV from buf[curV] (MFMA); sync; stage kt+2 -> buf[curV]; rotate.
// ---------------------------------------------------------------------------
__global__ __launch_bounds__(256) void attn(const unsigned short* __restrict__ Q,
                                            const char* __restrict__ Ksw,
                                            const char* __restrict__ Vsw,
                                            float* __restrict__ out,
                                            float* __restrict__ Obuf,
                                            float* __restrict__ mlbuf) {
    __shared__ __align__(16) char smem[32768];  // K dbuf [0,16K) | Vt dbuf [16K,32K)
    const int t = threadIdx.x, wave = t >> 6, lane = t & 63;
    const int lhi = lane >> 4, llo = lane & 15;
    // boustrophedon LPT: even rounds ascending bid, odd rounds reversed
    const int round = blockIdx.x >> 8, pos = blockIdx.x & 255;
    const int rank = (round & 1) ? (round << 8) + (255 - pos) : (int)blockIdx.x;
    int bh, qt, kts, kte;
    bool split; int part = 0;
    if (rank < 432) {
        bh = rank % 24;
        const int j = rank / 24;              // 0..17
        if (j < 16)      { qt = 16 + j; part = 0; kts = 0;  kte = 15; split = true;  }
        else if (j == 16){ qt = 15;              kts = 0;  kte = 15; split = false; }
        else             { qt = 31;     part = 1; kts = 16; kte = 31; split = true;  }
    } else {
        const int g = (rank - 432) / 48;      // 0..14, size s = 15-g
        const int r2 = (rank - 432) % 48;
        bh = r2 % 24;
        const int s = 15 - g;
        if (r2 / 24 == 0) { qt = s - 1;            kts = 0;  kte = qt; split = false; }
        else              { qt = s + 15; part = 1; kts = 16; kte = qt; split = true;  }
    }
    const unsigned short* Qg = Q + (size_t)bh * 2048 * 64;
    const char* Kg = Ksw + (size_t)bh * 32 * 8192;
    const char* Vg = Vsw + (size_t)bh * 32 * 8192;

    const int q0 = qt * 64 + wave * 16;      // lane's q-row = q0 + llo
    bf16x8 qa[2];
    #pragma unroll
    for (int kk = 0; kk < 2; ++kk)
        qa[kk] = *(const bf16x8*)(Qg + (size_t)(q0 + llo) * 64 + kk * 32 + lhi * 8);

    f32x4 acc[4] = {};                       // O^T: acc[n][r] -> e = n*16+lhi*4+r, q = llo
    float m_r = -1e30f, l_r = 0.f;

    #define ASTAGE(KT, BUF)                                              \
        do {                                                             \
            const char* ks_ = Kg + (size_t)(KT) * 8192;                  \
            const char* vs_ = Vg + (size_t)(KT) * 8192;                  \
            char* kd = smem + (BUF) * 8192;                              \
            char* vd = smem + 16384 + (BUF) * 8192;                      \
            gld16(ks_ + t * 16, kd + t * 16);                            \
            gld16(ks_ + t * 16 + 4096, kd + t * 16 + 4096);              \
            gld16(vs_ + t * 16, vd + t * 16);                            \
            gld16(vs_ + t * 16 + 4096, vd + t * 16 + 4096);              \
        } while (0)

    #define QKT(SC, KB)                                                          \
        do {                                                                     \
            __builtin_amdgcn_s_setprio(1);                                       \
            _Pragma("unroll")                                                    \
            for (int n = 0; n < 4; ++n) {                                        \
                f32x4 z = {};                                                    \
                _Pragma("unroll")                                                \
                for (int kk = 0; kk < 2; ++kk) {                                 \
                    bf16x8 bk = *(const bf16x8*)((KB) + sw(n * 16 + llo,         \
                                                           kk * 64 + lhi * 16)); \
                    z = MFMA16(bk, qa[kk], z);                                   \
                }                                                                \
                (SC)[n] = z;                                                     \
            }                                                                    \
            __builtin_amdgcn_s_setprio(0);                                       \
        } while (0)

    // prologue: stage tile kts, QK(kts), start staging kts+1
    ASTAGE(kts, 0);
    __syncthreads();
    f32x4 scA[4];
    QKT(scA, smem);
    if (kts < kte) ASTAGE(kts + 1, 1);

    int curV = 0;
    for (int kt = kts; kt <= kte; ++kt) {
        const bool haveNext = (kt < kte);
        f32x4 scB[4];
        if (haveNext) {
            __syncthreads();                  // buf[curV^1] fully staged (vmcnt0)
            QKT(scB, smem + (curV ^ 1) * 8192);   // issue next tile's QK early
        }
        // mask scA on the diagonal tile
        if (kt == qt) {
            #pragma unroll
            for (int n = 0; n < 4; ++n)
                #pragma unroll
                for (int r = 0; r < 4; ++r)
                    if (kt * 64 + n * 16 + lhi * 4 + r > q0 + llo) scA[n][r] = -1e30f;
        }
        // per-lane max over this lane's 16 scores (VALU: overlaps QK MFMAs)
        float pmax = fmaxf(
            fmaxf(fmaxf(fmaxf(scA[0][0], scA[0][1]), fmaxf(scA[0][2], scA[0][3])),
                  fmaxf(fmaxf(scA[1][0], scA[1][1]), fmaxf(scA[1][2], scA[1][3]))),
            fmaxf(fmaxf(fmaxf(scA[2][0], scA[2][1]), fmaxf(scA[2][2], scA[2][3])),
                  fmaxf(fmaxf(scA[3][0], scA[3][1]), fmaxf(scA[3][2], scA[3][3]))));
        if (__any(pmax > m_r + 8.0f)) {       // defer-max rescale
            float tm = fmaxf(pmax, __shfl_xor(pmax, 16, 64));
            tm = fmaxf(tm, __shfl_xor(tm, 32, 64));
            float nm = fmaxf(m_r, tm);
            float corr = exp2f(m_r - nm);     // first tile: -> 0
            m_r = nm;
            l_r *= corr;
            #pragma unroll
            for (int n = 0; n < 4; ++n)
                #pragma unroll
                for (int r = 0; r < 4; ++r) acc[n][r] *= corr;
        }
        // P = exp2(scA - m_r) packed into mfma16x16 B-fragments
        bf16x4 pf[4];
        float ps = 0.f;
        #pragma unroll
        for (int kb = 0; kb < 4; ++kb) {
            float p0 = exp2f(scA[kb][0] - m_r), p1 = exp2f(scA[kb][1] - m_r);
            float p2 = exp2f(scA[kb][2] - m_r), p3 = exp2f(scA[kb][3] - m_r);
            ps += (p0 + p1) + (p2 + p3);
            unsigned int w0, w1;
            asm("v_cvt_pk_bf16_f32 %0, %1, %2" : "=v"(w0) : "v"(p0), "v"(p1));
            asm("v_cvt_pk_bf16_f32 %0, %1, %2" : "=v"(w1) : "v"(p2), "v"(p3));
            unsigned long long u = ((unsigned long long)w1 << 32) | w0;
            pf[kb] = __builtin_bit_cast(bf16x4, u);
        }
        l_r += ps;
        // O^T += V^T P from buf[curV]
        {
            char* Vb = smem + 16384 + curV * 8192;
            __builtin_amdgcn_s_setprio(1);
            #pragma unroll
            for (int n = 0; n < 4; ++n) {
                const int row = n * 16 + llo;
                bf16x8 v8a = *(const bf16x8*)(Vb + sw(row, lhi * 32));
                bf16x8 v8b = *(const bf16x8*)(Vb + sw(row, lhi * 32 + 16));
                f32x4 a = acc[n];
                a = MFMAK16(__builtin_shufflevector(v8a, v8a, 0, 1, 2, 3), pf[0], a);
                a = MFMAK16(__builtin_shufflevector(v8a, v8a, 4, 5, 6, 7), pf[1], a);
                a = MFMAK16(__builtin_shufflevector(v8b, v8b, 0, 1, 2, 3), pf[2], a);
                a = MFMAK16(__builtin_shufflevector(v8b, v8b, 4, 5, 6, 7), pf[3], a);
                acc[n] = a;
            }
            __builtin_amdgcn_s_setprio(0);
        }
        // stage tile kt+2 into buf[curV] (after everyone is done reading it)
        if (kt + 1 < kte) {
            __syncthreads();
            ASTAGE(kt + 2, curV);
        }
        // rotate score buffer
        if (haveNext) {
            #pragma unroll
            for (int n = 0; n < 4; ++n) scA[n] = scB[n];
        }
        curV ^= 1;
    }
    #undef QKT
    #undef ASTAGE
    // finish the deferred l reduction (4 lhi partials of row q=llo)
    l_r += __shfl_xor(l_r, 16, 64);
    l_r += __shfl_xor(l_r, 32, 64);
    if (split) {
        const int p = ((bh * 16) + (qt - 16)) * 2 + part;
        float* Ob = Obuf + (size_t)p * 4096;
        const int qrow = wave * 16 + llo;    // 0..63 within tile
        #pragma unroll
        for (int n = 0; n < 4; ++n) {
            float4 o;
            o.x = acc[n][0]; o.y = acc[n][1]; o.z = acc[n][2]; o.w = acc[n][3];
            *(float4*)(Ob + qrow * 64 + n * 16 + lhi * 4) = o;
        }
        if (lhi == 0) {
            float2 ml; ml.x = m_r; ml.y = l_r;
            *(float2*)(mlbuf + (size_t)p * 128 + qrow * 2) = ml;
        }
    } else {
        const float inv = 1.0f / l_r;
        const int b = bh / 12, h = bh - b * 12;
        #pragma unroll
        for (int n = 0; n < 4; ++n) {
            float4 o;
            o.x = acc[n][0] * inv; o.y = acc[n][1] * inv;
            o.z = acc[n][2] * inv; o.w = acc[n][3] * inv;
            *(float4*)(out + (size_t)(b * 2048 + q0 + llo) * 768 + h * 64 + n * 16 + lhi * 4) = o;
        }
    }
}

// ---------------------------------------------------------------------------
// Kernel 4: combine split partials.  grid 384 (bh x qt>=16), 256 thr.
// ---------------------------------------------------------------------------
__global__ __launch_bounds__(256) void combine(const float* __restrict__ Obuf,
                                               const float* __restrict__ mlbuf,
                                               float* __restrict__ out) {
    const int bid = blockIdx.x;
    const int bh = bid % 24, qt = 16 + bid / 24;
    const int b = bh / 12, h = bh - b * 12;
    const int t = threadIdx.x;
    const int r = t >> 2, c0 = (t & 3) * 16;
    const int p0 = ((bh * 16) + (qt - 16)) * 2;
    const float2 ml0 = *(const float2*)(mlbuf + (size_t)p0 * 128 + r * 2);
    const float2 ml1 = *(const float2*)(mlbuf + (size_t)(p0 + 1) * 128 + r * 2);
    const float mm = fmaxf(ml0.x, ml1.x);
    const float w0 = exp2f(ml0.x - mm), w1 = exp2f(ml1.x - mm);
    const float inv = 1.0f / (ml0.y * w0 + ml1.y * w1);
    const float* s0 = Obuf + (size_t)p0 * 4096 + r * 64 + c0;
    const float* s1 = s0 + 4096;
    float* dst = out + (size_t)(b * 2048 + qt * 64 + r) * 768 + h * 64 + c0;
    #pragma unroll
    for (int i = 0; i < 4; ++i) {
        const float4 a = *(const float4*)(s0 + i * 4);
        const float4 c = *(const float4*)(s1 + i * 4);
        float4 o;
        o.x = (a.x * w0 + c.x * w1) * inv;
        o.y = (a.y * w0 + c.y * w1) * inv;
        o.z = (a.z * w0 + c.z * w1) * inv;
        o.w = (a.w * w0 + c.w * w1) * inv;
        *(float4*)(dst + i * 4) = o;
    }
}

// ---------------------------------------------------------------------------
extern "C" void kernel_launch(void* const* d_in, const int* in_sizes, int n_in,
                              void* d_out, int out_size, void* d_ws, size_t ws_size,
                              hipStream_t stream) {
    const float* x  = (const float*)d_in[0];
    const float* Wq = (const float*)d_in[1];
    const float* Wk = (const float*)d_in[2];
    const float* Wv = (const float*)d_in[3];
    float* out = (float*)d_out;

    char* ws = (char*)d_ws;
    char*           wtb   = ws;                                 // 3.54 MB
    unsigned short* q     = (unsigned short*)(ws + 3538944);    // 6.29 MB
    unsigned short* ksw   = (unsigned short*)(ws + 9830400);    // 6.29 MB
    char*           vsw   = (char*)(ws + 16121856);             // 6.29 MB
    char*           xb    = (char*)(ws + 22413312);             // 6.29 MB
    float*          Obuf  = (float*)(ws + 28704768);            // 12.58 MB
    float*          mlbuf = (float*)(ws + 41287680);            // 0.39 MB
    // requires ws_size >= 41680896 bytes

    hipLaunchKernelGGL(prep, dim3(1200), dim3(256), 0, stream, x, Wq, Wk, Wv, xb, wtb);
    hipLaunchKernelGGL(proj_qkv, dim3(64, 12), dim3(256), 0, stream,
                       xb, wtb, q, ksw, vsw);
    hipLaunchKernelGGL(attn, dim3(1152), dim3(256), 0, stream,
                       q, (const char*)ksw, vsw, out, Obuf, mlbuf);
    hipLaunchKernelGGL(combine, dim3(384), dim3(256), 0, stream, Obuf, mlbuf, out);
}

// Round 20
// 68.258 us; speedup vs baseline: 1.1834x; 1.0879x over previous
//
#include <hip/hip_runtime.h>
#include <hip/hip_bf16.h>

// MultiHeadAttention fused forward, MI355X/gfx950.
// B=2, S=2048, D_IN=768, H=12, D=64.  out[b,s,h*64+e] fp32.
//
// r20 = exact r14 reproduction (best measured: 68.4 us).  r15-r19 experiments
// (XCD locality, counted vmcnt, reg-GEMM proj, 2-group waves, 2-stage
// pipeline) were all null or negative and are reverted.
//
// Pipeline:
//   1. prep    : x -> bf16 pre-swizzled A-images; W -> pre-swizzled B-images.
//   2. proj_qkv: DMA-staged dbuf MFMA GEMM (r6-proven sync).  Q prescaled,
//                K/Vt pre-swizzled images.
//   3. attn    : SPLIT-K flash attention: every (bh,qt>=16) tile is two
//                independent <=16-iter blocks writing unnormalized (O,m,l)
//                partials; qt<16 tiles finish inline.  1152 blocks,
//                boustrophedon LPT order.  Swapped QK^T (lane-local softmax),
//                V LDS->reg hoisted after QK^T, in-register PV (mfma
//                16x16x16), defer-max, DMA dbuf staging, __syncthreads sync.
//   4. combine : merge split partials -> out.
//
// Workspace: wtb [0,3538944) | Q [3538944,9830400) | Ksw [9830400,16121856)
//            Vtsw [16121856,22413312) | xb [22413312,28704768)
//            Obuf [28704768,41287680) | mlbuf [41287680,41680896)

typedef short bf16x8 __attribute__((ext_vector_type(8)));
typedef short bf16x4 __attribute__((ext_vector_type(4)));
typedef float f32x4  __attribute__((ext_vector_type(4)));

#define MFMA16(a, b, c)  __builtin_amdgcn_mfma_f32_16x16x32_bf16((a), (b), (c), 0, 0, 0)
#define MFMAK16(a, b, c) __builtin_amdgcn_mfma_f32_16x16x16bf16_1k((a), (b), (c), 0, 0, 0)

static __device__ __forceinline__ unsigned short f2bf(float f) {
    unsigned int u = __builtin_bit_cast(unsigned int, f);
    u += 0x7fffu + ((u >> 16) & 1u);
    return (unsigned short)(u >> 16);
}

// XOR swizzle for [row][128B] tiles (conflict-free b128 column slices).
static __device__ __forceinline__ int sw(int row, int cb) {
    return (row << 7) + (cb ^ ((row & 7) << 4));
}

// async 16B global->LDS DMA (HW: wave-uniform LDS base + lane*16)
static __device__ __forceinline__ void gld16(const void* g, void* l) {
    __builtin_amdgcn_global_load_lds(
        (__attribute__((address_space(1))) void*)g,
        (__attribute__((address_space(3))) void*)l, 16, 0, 0);
}

// ---------------------------------------------------------------------------
// Kernel 1 (merged preps).  grid 1200.
// ---------------------------------------------------------------------------
__global__ __launch_bounds__(256) void prep(const float* __restrict__ x,
                                            const float* __restrict__ Wq,
                                            const float* __restrict__ Wk,
                                            const float* __restrict__ Wv,
                                            char* __restrict__ xb,
                                            char* __restrict__ wtb) {
    __shared__ float tile[64][65];
    const int bid = blockIdx.x;
    const int t = threadIdx.x;
    if (bid < 768) {
        const int stile = bid & 63, ks = bid >> 6;
        const int row = t >> 2, k16 = (t & 3) * 16;
        const float* src = x + (size_t)(stile * 64 + row) * 768 + ks * 64 + k16;
        char* img = xb + ((size_t)stile * 12 + ks) * 8192;
        const float4 v0 = *(const float4*)(src);
        const float4 v1 = *(const float4*)(src + 4);
        const float4 v2 = *(const float4*)(src + 8);
        const float4 v3 = *(const float4*)(src + 12);
        bf16x8 o0, o1;
        o0[0] = (short)f2bf(v0.x); o0[1] = (short)f2bf(v0.y);
        o0[2] = (short)f2bf(v0.z); o0[3] = (short)f2bf(v0.w);
        o0[4] = (short)f2bf(v1.x); o0[5] = (short)f2bf(v1.y);
        o0[6] = (short)f2bf(v1.z); o0[7] = (short)f2bf(v1.w);
        o1[0] = (short)f2bf(v2.x); o1[1] = (short)f2bf(v2.y);
        o1[2] = (short)f2bf(v2.z); o1[3] = (short)f2bf(v2.w);
        o1[4] = (short)f2bf(v3.x); o1[5] = (short)f2bf(v3.y);
        o1[6] = (short)f2bf(v3.z); o1[7] = (short)f2bf(v3.w);
        *(bf16x8*)(img + sw(row, k16 * 2)) = o0;
        *(bf16x8*)(img + sw(row, k16 * 2 + 16)) = o1;
    } else {
        const int idx = bid - 768;
        const int wh = idx % 36, dt = idx / 36;
        const int w = wh / 12, h = wh % 12;
        const float* W = (w == 0) ? Wq : (w == 1) ? Wk : Wv;
        for (int i = 0; i < 4; ++i) {
            int c = t + i * 256;
            int d = c >> 4, e4 = (c & 15) * 4;
            const float4 v = *(const float4*)(W + (size_t)(h * 768 + dt * 64 + d) * 64 + e4);
            tile[d][e4 + 0] = v.x; tile[d][e4 + 1] = v.y;
            tile[d][e4 + 2] = v.z; tile[d][e4 + 3] = v.w;
        }
        __syncthreads();
        char* img = wtb + ((size_t)(wh * 12) + dt) * 8192;
        for (int i = 0; i < 4; ++i) {
            int c = t + i * 256;
            int e = c >> 4, d4 = (c & 15) * 4;
            ushort4 o;
            o.x = f2bf(tile[d4 + 0][e]); o.y = f2bf(tile[d4 + 1][e]);
            o.z = f2bf(tile[d4 + 2][e]); o.w = f2bf(tile[d4 + 3][e]);
            *(ushort4*)(img + e * 128 + ((d4 * 2) ^ ((e & 7) << 4))) = o;
        }
    }
}

// ---------------------------------------------------------------------------
// Kernel 2: QKV projection.  grid (64 stile, 12 h), 4 waves, DMA dbuf.
// ---------------------------------------------------------------------------
__global__ __launch_bounds__(256) void proj_qkv(const char* __restrict__ xb,
                                                const char* __restrict__ wtb,
                                                unsigned short* __restrict__ q,
                                                unsigned short* __restrict__ ksw,
                                                char* __restrict__ vsw) {
    __shared__ __align__(16) char smem[65536];   // [2 buf][4 img][8192]
    const int stile = blockIdx.x;
    const int h = blockIdx.y;
    const int t = threadIdx.x;
    const int wave = t >> 6, lane = t & 63;
    const int lhi = lane >> 4, llo = lane & 15;
    const int wr = wave >> 1, wc = wave & 1;

    const char* asrc = xb + (size_t)stile * 12 * 8192;

    f32x4 acc[3][2][2] = {};

    #define STAGE(KS, BUF)                                                       \
        do {                                                                     \
            const char* s0 = asrc + (KS) * 8192;                                 \
            char* d0 = smem + (BUF) * 32768;                                     \
            gld16(s0 + t * 16, d0 + t * 16);                                     \
            gld16(s0 + t * 16 + 4096, d0 + t * 16 + 4096);                       \
            for (int w3 = 0; w3 < 3; ++w3) {                                     \
                const char* s1 = wtb + ((size_t)((w3 * 12 + h) * 12) + (KS)) * 8192; \
                char* d1 = smem + (BUF) * 32768 + (1 + w3) * 8192;               \
                gld16(s1 + t * 16, d1 + t * 16);                                 \
                gld16(s1 + t * 16 + 4096, d1 + t * 16 + 4096);                   \
            }                                                                    \
        } while (0)

    STAGE(0, 0);
    __syncthreads();
    int cur = 0;
    for (int ks = 0; ks < 12; ++ks) {
        if (ks < 11) STAGE(ks + 1, cur ^ 1);   // prefetch overlaps compute below
        char* Alds = smem + cur * 32768;
        #pragma unroll
        for (int kk = 0; kk < 2; ++kk) {
            bf16x8 a[2];
            #pragma unroll
            for (int m = 0; m < 2; ++m)
                a[m] = *(const bf16x8*)(Alds + sw(wr * 32 + m * 16 + llo, kk * 64 + lhi * 16));
            #pragma unroll
            for (int w3 = 0; w3 < 3; ++w3) {
                char* Blds = Alds + (1 + w3) * 8192;
                #pragma unroll
                for (int n = 0; n < 2; ++n) {
                    bf16x8 b = *(const bf16x8*)(Blds + sw(wc * 32 + n * 16 + llo, kk * 64 + lhi * 16));
                    #pragma unroll
                    for (int m = 0; m < 2; ++m)
                        acc[w3][m][n] = MFMA16(a[m], b, acc[w3][m][n]);
                }
            }
        }
        __syncthreads();   // drains DMA + orders buffer reuse
        cur ^= 1;
    }
    #undef STAGE

    const float SCALE_Q = 0.18033688011112042f;  // 0.125 * log2(e)
    const int bglob = stile >> 5, ktile = stile & 31;
    const int bh = bglob * 12 + h;
    #pragma unroll
    for (int m = 0; m < 2; ++m)
        for (int n = 0; n < 2; ++n)
            for (int r = 0; r < 4; ++r) {
                int s = (stile * 64 + wr * 32 + m * 16 + lhi * 4 + r) & 2047;
                int e = wc * 32 + n * 16 + llo;
                q[(size_t)(bh * 2048 + s) * 64 + e] = f2bf(acc[0][m][n][r] * SCALE_Q);
            }
    unsigned short* kdst = ksw + ((size_t)bh * 32 + ktile) * 4096;
    #pragma unroll
    for (int m = 0; m < 2; ++m)
        for (int n = 0; n < 2; ++n)
            for (int r = 0; r < 4; ++r) {
                int kk = wr * 32 + m * 16 + lhi * 4 + r;
                int e = wc * 32 + n * 16 + llo;
                kdst[kk * 64 + (e ^ ((kk & 7) << 3))] = f2bf(acc[1][m][n][r]);
            }
    char* vtimg = smem;
    __syncthreads();
    #pragma unroll
    for (int m = 0; m < 2; ++m)
        for (int n = 0; n < 2; ++n)
            for (int r = 0; r < 4; ++r) {
                int kk = wr * 32 + m * 16 + lhi * 4 + r;
                int e = wc * 32 + n * 16 + llo;
                int pos = (((kk >> 2) & 3) * 32 + (kk >> 4) * 8 + (kk & 3) * 2) ^ ((e & 7) << 4);
                *(unsigned short*)(vtimg + e * 128 + pos) = f2bf(acc[2][m][n][r]);
            }
    __syncthreads();
    {
        char* dst = vsw + ((size_t)bh * 32 + ktile) * 8192;
        #pragma unroll
        for (int i = 0; i < 2; ++i)
            *(float4*)(dst + t * 16 + i * 4096) =
                *(const float4*)(vtimg + t * 16 + i * 4096);
    }
}

// ---------------------------------------------------------------------------
// Kernel 3: split-K flash attention.  grid 1152 x 256 thr (4 waves).
// Blocks (boustrophedon LPT rank order, sizes descending):
//   rank<432      : size 16 — part0 of qt=16..31 | single qt=15 | part1 qt=31
//   rank>=432     : g=(rank-432)/48, size s=15-g: single qt=s-1 | part1 qt=s+15
// part0: kt 0..15 (no diag); part1: kt 16..qt (diag); single: kt 0..qt (diag).
// Split blocks write unnormalized fp32 (O,m,l) partials; singles write out.
// ---------------------------------------------------------------------------
__global__ __launch_bounds__(256) void attn(const unsigned short* __restrict__ Q,
                                            const char* __restrict__ Ksw,
                                            const char* __restrict__ Vsw,
                                            float* __restrict__ out,
                                            float* __restrict__ Obuf,
                                            float* __restrict__ mlbuf) {
    __shared__ __align__(16) char smem[32768];  // K dbuf [0,16K) | Vt dbuf [16K,32K)
    const int t = threadIdx.x, wave = t >> 6, lane = t & 63;
    const int lhi = lane >> 4, llo = lane & 15;
    // boustrophedon LPT: even rounds ascending bid, odd rounds reversed
    const int round = blockIdx.x >> 8, pos = blockIdx.x & 255;
    const int rank = (round & 1) ? (round << 8) + (255 - pos) : (int)blockIdx.x;
    int bh, qt, kts, kte;
    bool split; int part = 0;
    if (rank < 432) {
        bh = rank % 24;
        const int j = rank / 24;              // 0..17
        if (j < 16)      { qt = 16 + j; part = 0; kts = 0;  kte = 15; split = true;  }
        else if (j == 16){ qt = 15;              kts = 0;  kte = 15; split = false; }
        else             { qt = 31;     part = 1; kts = 16; kte = 31; split = true;  }
    } else {
        const int g = (rank - 432) / 48;      // 0..14, size s = 15-g
        const int r2 = (rank - 432) % 48;
        bh = r2 % 24;
        const int s = 15 - g;
        if (r2 / 24 == 0) { qt = s - 1;            kts = 0;  kte = qt; split = false; }
        else              { qt = s + 15; part = 1; kts = 16; kte = qt; split = true;  }
    }
    const unsigned short* Qg = Q + (size_t)bh * 2048 * 64;
    const char* Kg = Ksw + (size_t)bh * 32 * 8192;
    const char* Vg = Vsw + (size_t)bh * 32 * 8192;

    const int q0 = qt * 64 + wave * 16;      // lane's q-row = q0 + llo
    bf16x8 qa[2];
    #pragma unroll
    for (int kk = 0; kk < 2; ++kk)
        qa[kk] = *(const bf16x8*)(Qg + (size_t)(q0 + llo) * 64 + kk * 32 + lhi * 8);

    f32x4 acc[4] = {};                       // O^T: acc[n][r] -> e = n*16+lhi*4+r, q = llo
    float m_r = -1e30f, l_r = 0.f;

    #define ASTAGE(KT, BUF)                                              \
        do {                                                             \
            const char* ks_ = Kg + (size_t)(KT) * 8192;                  \
            const char* vs_ = Vg + (size_t)(KT) * 8192;                  \
            char* kd = smem + (BUF) * 8192;                              \
            char* vd = smem + 16384 + (BUF) * 8192;                      \
            gld16(ks_ + t * 16, kd + t * 16);                            \
            gld16(ks_ + t * 16 + 4096, kd + t * 16 + 4096);              \
            gld16(vs_ + t * 16, vd + t * 16);                            \
            gld16(vs_ + t * 16 + 4096, vd + t * 16 + 4096);              \
        } while (0)

    ASTAGE(kts, 0);
    __syncthreads();
    int cur = 0;
    for (int kt = kts; kt <= kte; ++kt) {
        if (kt < kte) ASTAGE(kt + 1, cur ^ 1);   // prefetch overlaps compute below
        char* Kb = smem + cur * 8192;
        char* Vb = smem + 16384 + cur * 8192;

        // S^T = K Q^T: sc[n][r] -> k-pos = n*16+lhi*4+r, q = llo
        f32x4 sc[4];
        __builtin_amdgcn_s_setprio(1);
        #pragma unroll
        for (int n = 0; n < 4; ++n) {
            f32x4 z = {};
            #pragma unroll
            for (int kk = 0; kk < 2; ++kk) {
                bf16x8 bk = *(const bf16x8*)(Kb + sw(n * 16 + llo, kk * 64 + lhi * 16));
                z = MFMA16(bk, qa[kk], z);
            }
            sc[n] = z;
        }
        __builtin_amdgcn_s_setprio(0);
        // V fragments -> registers (LDS pipe overlaps softmax below)
        bf16x8 vfr[4][2];
        #pragma unroll
        for (int n = 0; n < 4; ++n) {
            const int row = n * 16 + llo;
            vfr[n][0] = *(const bf16x8*)(Vb + sw(row, lhi * 32));
            vfr[n][1] = *(const bf16x8*)(Vb + sw(row, lhi * 32 + 16));
        }
        if (kt == qt) {   // causal mask, diagonal tile only (part0 never hits)
            #pragma unroll
            for (int n = 0; n < 4; ++n)
                #pragma unroll
                for (int r = 0; r < 4; ++r)
                    if (kt * 64 + n * 16 + lhi * 4 + r > q0 + llo) sc[n][r] = -1e30f;
        }
        // per-lane max over this lane's 16 scores
        float pmax = fmaxf(
            fmaxf(fmaxf(fmaxf(sc[0][0], sc[0][1]), fmaxf(sc[0][2], sc[0][3])),
                  fmaxf(fmaxf(sc[1][0], sc[1][1]), fmaxf(sc[1][2], sc[1][3]))),
            fmaxf(fmaxf(fmaxf(sc[2][0], sc[2][1]), fmaxf(sc[2][2], sc[2][3])),
                  fmaxf(fmaxf(sc[3][0], sc[3][1]), fmaxf(sc[3][2], sc[3][3]))));
        // defer-max: rescale only if some row's max grew by > 8 (exp2 units)
        if (__any(pmax > m_r + 8.0f)) {
            float tm = fmaxf(pmax, __shfl_xor(pmax, 16, 64));
            tm = fmaxf(tm, __shfl_xor(tm, 32, 64));
            float nm = fmaxf(m_r, tm);
            float corr = exp2f(m_r - nm);             // first tile: -> 0
            m_r = nm;
            l_r *= corr;
            #pragma unroll
            for (int n = 0; n < 4; ++n)
                #pragma unroll
                for (int r = 0; r < 4; ++r) acc[n][r] *= corr;
        }
        // P = exp2(sc - m_r), packed straight into mfma16x16 B-fragments
        bf16x4 pf[4];
        float ps = 0.f;
        #pragma unroll
        for (int kb = 0; kb < 4; ++kb) {
            float p0 = exp2f(sc[kb][0] - m_r), p1 = exp2f(sc[kb][1] - m_r);
            float p2 = exp2f(sc[kb][2] - m_r), p3 = exp2f(sc[kb][3] - m_r);
            ps += (p0 + p1) + (p2 + p3);
            unsigned int w0, w1;
            asm("v_cvt_pk_bf16_f32 %0, %1, %2" : "=v"(w0) : "v"(p0), "v"(p1));
            asm("v_cvt_pk_bf16_f32 %0, %1, %2" : "=v"(w1) : "v"(p2), "v"(p3));
            unsigned long long u = ((unsigned long long)w1 << 32) | w0;
            pf[kb] = __builtin_bit_cast(bf16x4, u);
        }
        l_r += ps;
        // O^T += V^T P — PV entirely from registers (vfr + pf)
        __builtin_amdgcn_s_setprio(1);
        #pragma unroll
        for (int n = 0; n < 4; ++n) {
            f32x4 a = acc[n];
            a = MFMAK16(__builtin_shufflevector(vfr[n][0], vfr[n][0], 0, 1, 2, 3), pf[0], a);
            a = MFMAK16(__builtin_shufflevector(vfr[n][0], vfr[n][0], 4, 5, 6, 7), pf[1], a);
            a = MFMAK16(__builtin_shufflevector(vfr[n][1], vfr[n][1], 0, 1, 2, 3), pf[2], a);
            a = MFMAK16(__builtin_shufflevector(vfr[n][1], vfr[n][1], 4, 5, 6, 7), pf[3], a);
            acc[n] = a;
        }
        __builtin_amdgcn_s_setprio(0);
        if (kt < kte) __syncthreads();   // drains DMA + orders buffer reuse
        cur ^= 1;
    }
    #undef ASTAGE
    // finish the deferred l reduction (4 lhi partials of row q=llo)
    l_r += __shfl_xor(l_r, 16, 64);
    l_r += __shfl_xor(l_r, 32, 64);
    if (split) {
        // unnormalized partial: O (fp32), m, l
        const int p = ((bh * 16) + (qt - 16)) * 2 + part;
        float* Ob = Obuf + (size_t)p * 4096;
        const int qrow = wave * 16 + llo;    // 0..63 within tile
        #pragma unroll
        for (int n = 0; n < 4; ++n) {
            float4 o;
            o.x = acc[n][0]; o.y = acc[n][1]; o.z = acc[n][2]; o.w = acc[n][3];
            *(float4*)(Ob + qrow * 64 + n * 16 + lhi * 4) = o;
        }
        if (lhi == 0) {
            float2 ml; ml.x = m_r; ml.y = l_r;
            *(float2*)(mlbuf + (size_t)p * 128 + qrow * 2) = ml;
        }
    } else {
        const float inv = 1.0f / l_r;
        const int b = bh / 12, h = bh - b * 12;
        #pragma unroll
        for (int n = 0; n < 4; ++n) {
            float4 o;
            o.x = acc[n][0] * inv; o.y = acc[n][1] * inv;
            o.z = acc[n][2] * inv; o.w = acc[n][3] * inv;
            *(float4*)(out + (size_t)(b * 2048 + q0 + llo) * 768 + h * 64 + n * 16 + lhi * 4) = o;
        }
    }
}

// ---------------------------------------------------------------------------
// Kernel 4: combine split partials.  grid 384 (bh x qt>=16), 256 thr.
// O = (O0*w0 + O1*w1) / (l0*w0 + l1*w1), w_i = 2^(m_i - max(m0,m1)).
// ---------------------------------------------------------------------------
__global__ __launch_bounds__(256) void combine(const float* __restrict__ Obuf,
                                               const float* __restrict__ mlbuf,
                                               float* __restrict__ out) {
    const int bid = blockIdx.x;
    const int bh = bid % 24, qt = 16 + bid / 24;
    const int b = bh / 12, h = bh - b * 12;
    const int t = threadIdx.x;
    const int r = t >> 2, c0 = (t & 3) * 16;
    const int p0 = ((bh * 16) + (qt - 16)) * 2;
    const float2 ml0 = *(const float2*)(mlbuf + (size_t)p0 * 128 + r * 2);
    const float2 ml1 = *(const float2*)(mlbuf + (size_t)(p0 + 1) * 128 + r * 2);
    const float mm = fmaxf(ml0.x, ml1.x);
    const float w0 = exp2f(ml0.x - mm), w1 = exp2f(ml1.x - mm);
    const float inv = 1.0f / (ml0.y * w0 + ml1.y * w1);
    const float* s0 = Obuf + (size_t)p0 * 4096 + r * 64 + c0;
    const float* s1 = s0 + 4096;
    float* dst = out + (size_t)(b * 2048 + qt * 64 + r) * 768 + h * 64 + c0;
    #pragma unroll
    for (int i = 0; i < 4; ++i) {
        const float4 a = *(const float4*)(s0 + i * 4);
        const float4 c = *(const float4*)(s1 + i * 4);
        float4 o;
        o.x = (a.x * w0 + c.x * w1) * inv;
        o.y = (a.y * w0 + c.y * w1) * inv;
        o.z = (a.z * w0 + c.z * w1) * inv;
        o.w = (a.w * w0 + c.w * w1) * inv;
        *(float4*)(dst + i * 4) = o;
    }
}

// ---------------------------------------------------------------------------
extern "C" void kernel_launch(void* const* d_in, const int* in_sizes, int n_in,
                              void* d_out, int out_size, void* d_ws, size_t ws_size,
                              hipStream_t stream) {
    const float* x  = (const float*)d_in[0];
    const float* Wq = (const float*)d_in[1];
    const float* Wk = (const float*)d_in[2];
    const float* Wv = (const float*)d_in[3];
    float* out = (float*)d_out;

    char* ws = (char*)d_ws;
    char*           wtb   = ws;                                 // 3.54 MB
    unsigned short* q     = (unsigned short*)(ws + 3538944);    // 6.29 MB
    unsigned short* ksw   = (unsigned short*)(ws + 9830400);    // 6.29 MB
    char*           vsw   = (char*)(ws + 16121856);             // 6.29 MB
    char*           xb    = (char*)(ws + 22413312);             // 6.29 MB
    float*          Obuf  = (float*)(ws + 28704768);            // 12.58 MB
    float*          mlbuf = (float*)(ws + 41287680);            // 0.39 MB
    // requires ws_size >= 41680896 bytes

    hipLaunchKernelGGL(prep, dim3(1200), dim3(256), 0, stream, x, Wq, Wk, Wv, xb, wtb);
    hipLaunchKernelGGL(proj_qkv, dim3(64, 12), dim3(256), 0, stream,
                       xb, wtb, q, ksw, vsw);
    hipLaunchKernelGGL(attn, dim3(1152), dim3(256), 0, stream,
                       q, (const char*)ksw, vsw, out, Obuf, mlbuf);
    hipLaunchKernelGGL(combine, dim3(384), dim3(256), 0, stream, Obuf, mlbuf, out);
}